// Round 7
// baseline (129.641 us; speedup 1.0000x reference)
//
#include <hip/hip_runtime.h>
#include <hip/hip_bf16.h>
#include <math.h>

#define NB 32     // batch
#define NH 32     // query heads
#define HKV 8     // kv heads
#define GQ 4      // NH / HKV
#define DH 128    // head dim
#define BS 16     // paged block size
#define BPS 128   // blocks per seq
#define MAXC 2048 // max context (BPS * BS)
#define NSPLIT 16 // flash-decoding splits per (b, kvh)
#define TILE 16   // positions per LDS tile (18.7 KB LDS -> 8 blocks/CU)
#define HSTR 132  // per-head partial: acc[128], m, l, pad2
#define PART_STRIDE (GQ * HSTR)   // 528 floats per (b,kvh,split)

typedef __attribute__((ext_vector_type(4))) float f32x4;

__device__ __forceinline__ float bf16r(float x) {
    return __bfloat162float(__float2bfloat16(x));
}

// ---------------- Kernel 1: fused rowidx + RoPE ------------------------------
// rowidx[b*MAXC + t] >= 0 : flat cache row; < 0 : -(j+1) -> new kv of batch j.
// Blocks 0..31 additionally apply bf16-cache-exact RoPE for batch bid.
__global__ void prep_kernel(const float* __restrict__ q,
                            const float* __restrict__ knew,
                            const int* __restrict__ bt,
                            const int* __restrict__ ctx,
                            float* __restrict__ q_rot,
                            float* __restrict__ k_rot,
                            int* __restrict__ rowidx)
{
    __shared__ int slot_l[NB];
    int tid = threadIdx.x, bid = blockIdx.x;
    if (tid < NB) {
        int last = ctx[tid] - 1;
        slot_l[tid] = bt[tid * BPS + (last >> 4)] * BS + (last & 15);
    }
    __syncthreads();

    int g = bid * 256 + tid;              // g = b*MAXC + t
    int b = g >> 11;
    int t = g & (MAXC - 1);
    int flat = bt[b * BPS + (t >> 4)] * BS + (t & 15);
    int o = flat;
    #pragma unroll
    for (int j = 0; j < NB; ++j)
        if (flat == slot_l[j]) o = -(j + 1);
    rowidx[g] = o;

    if (bid < NB) {                       // RoPE for batch `bid`
        int rb  = bid;
        int d   = tid & 127;              // dim
        int hi  = tid >> 7;               // 0/1: head-range split
        int pos = ctx[rb];
        int i2  = d & 63;
        // Mimic: inv = bf16(1/10000^(i/64)), t = bf16(pos), fr = bf16(t*inv),
        // cos/sin f32-computed then bf16-rounded (XLA bf16 semantics).
        float e   = (float)i2 * (1.0f / 64.0f);
        float pf  = (float)pow(10000.0, (double)e);
        float inv = bf16r(1.0f / pf);
        float tb  = bf16r((float)pos);
        float fr  = bf16r(tb * inv);
        float c   = bf16r(cosf(fr));
        float s   = bf16r(sinf(fr));

        const float* qb = q + (size_t)rb * NH * DH;
        float* qo = q_rot + (size_t)rb * NH * DH;
        #pragma unroll 4
        for (int h = hi * 16; h < hi * 16 + 16; ++h) {
            float x  = qb[h * DH + d];
            float xr = (d < 64) ? -qb[h * DH + d + 64] : qb[h * DH + d - 64];
            qo[h * DH + d] = x * c + xr * s;
        }
        const float* kb = knew + (size_t)rb * HKV * DH;
        float* ko = k_rot + (size_t)rb * HKV * DH;
        #pragma unroll
        for (int h = hi * 4; h < hi * 4 + 4; ++h) {
            float x  = kb[h * DH + d];
            float xr = (d < 64) ? -kb[h * DH + d + 64] : kb[h * DH + d - 64];
            ko[h * DH + d] = x * c + xr * s;
        }
    }
}

// ---------------- Kernel 2: attention partials -------------------------------
// R3 structure (best: 78.6 us) tuned for max memory concurrency:
//  - TILE=16 -> 18.7 KB LDS -> 8 blocks/CU; __launch_bounds__(256,8) forces
//    <=64 VGPR -> 32 waves/CU (2x round-3 occupancy = 2x outstanding misses).
//  - nontemporal loads on the streamed KV gather (data is never reused).
//  - register double-buffer prefetch (named regs k0,k1,v0,v1 -> no scratch).
// Wave = one q-head; lane (quad=lane>>4, l=lane&15): quarter-dot of q.K[l].
__global__ __launch_bounds__(256, 8) void attn_partial(
    const float* __restrict__ kc, const float* __restrict__ vc,
    const float* __restrict__ vnew,
    const int* __restrict__ ctx,
    const float* __restrict__ q_rot, const float* __restrict__ k_rot,
    const int* __restrict__ rowidx, float* __restrict__ part)
{
    __shared__ float q_lds[GQ][DH];
    __shared__ float k_lds[TILE][DH];   // f4-col c of row r stored at (c ^ r)
    __shared__ float v_lds[TILE][DH];
    __shared__ float p_lds[GQ][TILE];

    int tid = threadIdx.x;
    int bid = blockIdx.x;
    int b   = bid & 31;
    int kvh = (bid >> 5) & 7;
    int sp  = bid >> 8;                   // 0..15

    int L = ctx[b];
    int chunk = (L + NSPLIT - 1) / NSPLIT;
    int start = sp * chunk;
    int end   = min(L, start + chunk);    // may be <= start: zero partial

    {   // stage q (4 heads x 128, contiguous)
        const float* qs = q_rot + ((size_t)b * NH + kvh * GQ) * DH;
        ((float*)q_lds)[tid]       = qs[tid];
        ((float*)q_lds)[tid + 256] = qs[tid + 256];
    }

    int lane = tid & 63;
    int h    = tid >> 6;      // wave == head index (0..3)
    int l    = lane & 15;     // position within tile
    int quad = lane >> 4;     // which 32-float quarter of the dot
    int rr   = tid >> 5;      // staging row base (0..7)
    int c4   = tid & 31;      // staging f4 column

    float  m_run = -INFINITY;
    float  s_run = 0.0f;
    float2 acc   = make_float2(0.f, 0.f);

    f32x4 k0, k1, v0, v1;     // named prefetch regs (arrays spill - round 2)

    // Unconditional clamped gather (end-1 >= 0 since L >= 1); K and V share
    // the same row offset. Nontemporal: streamed once, never reused.
#define GATHER(T, KD, VD)                                                    \
    {                                                                        \
        int tt = min((T), end - 1);                                          \
        int o  = __builtin_nontemporal_load(rowidx + ((b << 11) | tt));      \
        size_t off = (o >= 0) ? (size_t)o * (HKV * DH) + kvh * DH            \
                              : ((size_t)(-o - 1) * HKV + kvh) * DH;         \
        const f32x4* kp = (const f32x4*)(((o >= 0) ? kc : k_rot) + off);     \
        const f32x4* vp = (const f32x4*)(((o >= 0) ? vc : vnew) + off);      \
        KD = __builtin_nontemporal_load(kp + c4);                            \
        VD = __builtin_nontemporal_load(vp + c4);                            \
    }

    GATHER(start + rr,     k0, v0);       // prologue prefetch
    GATHER(start + rr + 8, k1, v1);
    __syncthreads();                      // q_lds visible

    for (int t0 = start; t0 < end; t0 += TILE) {
        int n = min(TILE, end - t0);

        // write prefetched regs to LDS (vmcnt wait lands here)
        if (t0 + rr < end) {
            int sc = (c4 ^ rr) * 4;
            *(f32x4*)&k_lds[rr][sc] = k0;
            *(f32x4*)&v_lds[rr][sc] = v0;
        }
        if (t0 + rr + 8 < end) {
            int sc = (c4 ^ (rr + 8)) * 4;
            *(f32x4*)&k_lds[rr + 8][sc] = k1;
            *(f32x4*)&v_lds[rr + 8][sc] = v1;
        }
        __syncthreads();

        GATHER(t0 + TILE + rr,     k0, v0);   // next tile in flight
        GATHER(t0 + TILE + rr + 8, k1, v1);   // during compute below

        // scores: lane (quad, l) computes quarter-dot q[h] . K[l]
        float s = 0.f;
        if (l < n) {
            const float4* qrow = (const float4*)q_lds[h];
            #pragma unroll
            for (int k = 0; k < 8; ++k) {
                int j = quad * 8 + k;
                float4 a  = qrow[j];
                float4 bb = *(const float4*)&k_lds[l][(j ^ l) * 4];
                s += a.x * bb.x + a.y * bb.y + a.z * bb.z + a.w * bb.w;
            }
        }
        s += __shfl_xor(s, 16);           // sum the 4 quarters
        s += __shfl_xor(s, 32);
        s *= 0.08838834764831845f;        // D^-0.5

        float sm = (l < n) ? s : -INFINITY;
        float tm = sm;
        #pragma unroll
        for (int off = 8; off >= 1; off >>= 1)     // 16 l-values per group
            tm = fmaxf(tm, __shfl_xor(tm, off));
        float mnew = fmaxf(m_run, tm);
        float p  = (l < n) ? __expf(s - mnew) : 0.f;
        float ts = p;
        #pragma unroll
        for (int off = 8; off >= 1; off >>= 1)
            ts += __shfl_xor(ts, off);
        float r = __expf(m_run - mnew);   // first tile: exp(-inf) = 0
        s_run = s_run * r + ts;
        m_run = mnew;
        acc.x *= r; acc.y *= r;
        // p_lds[h][*] is wave-private; per-wave DS ops are in-order -> no
        // barrier between this write and the PV reads below.
        if (lane < TILE) p_lds[h][l] = p;

        // PV: lane owns d = lane*2, lane*2+1 (f4-col = lane>>1, sub = lane&1)
        int jc = lane >> 1, sub = lane & 1;
        for (int ll = 0; ll < n; ++ll) {
            float pv = p_lds[h][ll];
            const float2 vv = *(const float2*)&v_lds[ll][((jc ^ ll) << 2) + sub * 2];
            acc.x += pv * vv.x;
            acc.y += pv * vv.y;
        }
        __syncthreads();   // all reads done before next tile's ds_write
    }

    float* pp = part + (size_t)((b * HKV + kvh) * NSPLIT + sp) * PART_STRIDE
              + h * HSTR;
    *(float2*)&pp[lane * 2] = acc;
    if (lane == 0) { pp[128] = m_run; pp[129] = s_run; }
}

// ---------------- Kernel 3: combine split partials ---------------------------
__global__ void reduce_kernel(const float* __restrict__ part,
                              float* __restrict__ out)
{
    int blk = blockIdx.x;    // b*32 + hq
    int d   = threadIdx.x;   // 0..127
    int b   = blk >> 5;
    int hq  = blk & 31;
    int kvh = hq >> 2;
    int g   = hq & 3;
    const float* base = part + (size_t)((b * HKV + kvh) * NSPLIT) * PART_STRIDE
                      + g * HSTR;

    float M = -INFINITY;
    #pragma unroll
    for (int s = 0; s < NSPLIT; ++s)
        M = fmaxf(M, base[(size_t)s * PART_STRIDE + 128]);
    float S = 0.f, acc = 0.f;
    #pragma unroll
    for (int s = 0; s < NSPLIT; ++s) {
        float ms = base[(size_t)s * PART_STRIDE + 128];
        float f  = __expf(ms - M);     // empty split: exp(-inf)=0
        S   += base[(size_t)s * PART_STRIDE + 129] * f;
        acc += base[(size_t)s * PART_STRIDE + d] * f;
    }
    out[(size_t)blk * DH + d] = acc / S;
}

extern "C" void kernel_launch(void* const* d_in, const int* in_sizes, int n_in,
                              void* d_out, int out_size, void* d_ws, size_t ws_size,
                              hipStream_t stream)
{
    const float* q    = (const float*)d_in[0];
    const float* knew = (const float*)d_in[1];
    const float* vnew = (const float*)d_in[2];
    const float* kc   = (const float*)d_in[3];
    const float* vc   = (const float*)d_in[4];
    const int*   bt   = (const int*)d_in[5];
    const int*   ctx  = (const int*)d_in[6];
    float* out = (float*)d_out;

    float* ws     = (float*)d_ws;
    float* q_rot  = ws;                              // 32*32*128 = 131072 f
    float* k_rot  = ws + 131072;                     // 32*8*128  =  32768 f
    int*   rowidx = (int*)(ws + 131072 + 32768);     // 32*2048   =  65536 i
    float* part   = ws + 131072 + 32768 + 65536;     // 32*8*16*528 = 2162688 f

    prep_kernel<<<NB * MAXC / 256, 256, 0, stream>>>(q, knew, bt, ctx,
                                                     q_rot, k_rot, rowidx);
    attn_partial<<<NB * HKV * NSPLIT, 256, 0, stream>>>(
        kc, vc, vnew, ctx, q_rot, k_rot, rowidx, part);
    reduce_kernel<<<NB * NH, 128, 0, stream>>>(part, out);
}